// Round 8
// baseline (17528.661 us; speedup 1.0000x reference)
//
#include <hip/hip_runtime.h>

#define T_STEPS 256
#define H_DIM   1024
#define L_CTX   200
#define CTXD    512
#define A_DIM   512
#define G4      4096
#define KTOT    3584   // 1024 h + 1024 par + 1024 hctx + 512 ctx
#define NBLK    64
#define NTHR    1024

typedef __attribute__((ext_vector_type(8))) unsigned short us8;

// ws offsets (floats)
#define OFF_XWB    0                           // 256*4096
#define OFF_CTXW   (OFF_XWB   + T_STEPS*G4)    // 200*512
#define OFF_CTXT   (OFF_CTXW  + L_CTX*A_DIM)   // 512*200
#define OFF_U      (OFF_CTXT  + CTXD*L_CTX)    // 512
#define OFF_W      (OFF_U     + A_DIM)         // 512
#define OFF_EC     (OFF_W     + A_DIM)         // 256
#define OFF_EH     (OFF_EC    + 256)           // 256
#define OFF_CTXV   (OFF_EH    + 256)           // 512
#define OFF_HCTX   (OFF_CTXV  + CTXD)          // 1024
#define OFF_HBUF   (OFF_HCTX  + H_DIM)         // 1024
#define OFF_HIST   (OFF_HBUF  + H_DIM)         // 256*1024
#define OFF_HISTT  (OFF_HIST  + T_STEPS*H_DIM) // 1024*256
#define OFF_HISTW  (OFF_HISTT + H_DIM*T_STEPS) // 256*512
#define OFF_W4T    (OFF_HISTW + T_STEPS*A_DIM) // 4096*3584 bf16
#define OFF_WT3    (OFF_W4T   + G4*KTOT/2)     // 1536*1024 bf16
#define OFF_BAR    (OFF_WT3   + 1536*H_DIM/2)  // 64 flag dwords
#define WS_FLOATS  (OFF_BAR   + 256)

__device__ __forceinline__ float sigmoidf_(float x) { return 1.f / (1.f + __expf(-x)); }
__device__ __forceinline__ float bf2f(unsigned short h) { return __uint_as_float((unsigned)h << 16); }
__device__ __forceinline__ unsigned short f2bf(float x) {
    unsigned u = __float_as_uint(x);
    return (unsigned short)((u + 0x7FFFu + ((u >> 16) & 1u)) >> 16);
}
// coherent-point (agent-scope) accesses: bypass non-coherent per-XCD L2
__device__ __forceinline__ float ld_ag(const float* p) {
    return __hip_atomic_load((float*)p, __ATOMIC_RELAXED, __HIP_MEMORY_SCOPE_AGENT);
}
__device__ __forceinline__ void st_ag(float* p, float v) {
    __hip_atomic_store(p, v, __ATOMIC_RELAXED, __HIP_MEMORY_SCOPE_AGENT);
}
__device__ __forceinline__ float wred(float x) {
    #pragma unroll
    for (int off = 32; off; off >>= 1) x += __shfl_down(x, off);
    return x;
}

// RMW-free flag barrier: block b STOREs phase to bar[b]; wave 0 gather-polls
// all 64 flags (one 64-lane relaxed load per round). __syncthreads() before
// arrival drains vmcnt => prior st_ag data is visible before the flag is.
__device__ __forceinline__ void gbar(unsigned* bar, int b, unsigned ph) {
    __syncthreads();
    if (threadIdx.x < 64) {
        if (threadIdx.x == 0)
            __hip_atomic_store(bar + b, ph, __ATOMIC_RELAXED, __HIP_MEMORY_SCOPE_AGENT);
        int spins = 0;
        unsigned vflag;
        do {
            vflag = __hip_atomic_load(bar + threadIdx.x, __ATOMIC_RELAXED, __HIP_MEMORY_SCOPE_AGENT);
            if (++spins > 50000) break;  // hang insurance
        } while (__any(vflag < ph));
    }
    __syncthreads();
}

// ---------- prep kernels ----------

__global__ __launch_bounds__(256) void k_xwb(const float* __restrict__ X,
                                             const float* __restrict__ Wx,
                                             const float* __restrict__ b4,
                                             float* __restrict__ XWb) {
    int c  = blockIdx.x * 256 + threadIdx.x;
    int r0 = blockIdx.y * 8;
    float acc[8] = {0,0,0,0,0,0,0,0};
    for (int k = 0; k < 512; ++k) {
        float wv = Wx[(size_t)k * G4 + c];
        #pragma unroll
        for (int r = 0; r < 8; ++r) acc[r] += X[(r0 + r) * 512 + k] * wv;
    }
    float bb = b4[c];
    #pragma unroll
    for (int r = 0; r < 8; ++r) XWb[(size_t)(r0 + r) * G4 + c] = acc[r] + bb;
}

__global__ __launch_bounds__(256) void k_ctxw(const float* __restrict__ ctx,
                                              const float* __restrict__ Wctx,
                                              const float* __restrict__ bctx,
                                              float* __restrict__ ctxW) {
    int a  = blockIdx.x * 256 + threadIdx.x;
    int l0 = blockIdx.y * 8;
    float acc[8] = {0,0,0,0,0,0,0,0};
    for (int k = 0; k < 512; ++k) {
        float wv = Wctx[(size_t)k * A_DIM + a];
        #pragma unroll
        for (int r = 0; r < 8; ++r) acc[r] += ctx[(l0 + r) * CTXD + k] * wv;
    }
    float bb = bctx[a];
    #pragma unroll
    for (int r = 0; r < 8; ++r) ctxW[(l0 + r) * A_DIM + a] = acc[r] + bb;
}

__global__ __launch_bounds__(256) void k_packW4(const float* __restrict__ Uh,
                                                const float* __restrict__ Ph,
                                                const float* __restrict__ Hh,
                                                const float* __restrict__ Cc,
                                                unsigned short* __restrict__ W4T) {
    __shared__ float tile[32][33];
    const int k0 = blockIdx.x * 32, d0 = blockIdx.y * 32, q = blockIdx.z;
    const int x = threadIdx.x & 31, yy = threadIdx.x >> 5;
    const int c = q * 1024 + d0 + x;
    #pragma unroll
    for (int i = 0; i < 32; i += 8) {
        int ka = k0 + yy + i;
        const float* src; int kk;
        if (ka < 1024)      { src = Uh; kk = ka; }
        else if (ka < 2048) { src = Ph; kk = ka - 1024; }
        else if (ka < 3072) { src = Hh; kk = ka - 2048; }
        else                { src = Cc; kk = ka - 3072; }
        tile[yy + i][x] = src[(size_t)kk * G4 + c];
    }
    __syncthreads();
    #pragma unroll
    for (int i = 0; i < 32; i += 8) {
        int dd = yy + i;
        int col = 4 * (d0 + dd) + q;
        W4T[(size_t)col * KTOT + k0 + x] = f2bf(tile[x][dd]);
    }
}

__global__ __launch_bounds__(256) void k_packW3(const float* __restrict__ Wh,
                                                const float* __restrict__ Whh,
                                                const float* __restrict__ Whist,
                                                unsigned short* __restrict__ WT3) {
    __shared__ float tile[32][33];
    const int k0 = blockIdx.x * 32, c0 = blockIdx.y * 32, s = blockIdx.z;
    const float* S = (s == 0) ? Wh : (s == 1) ? Whh : Whist;
    const int x = threadIdx.x & 31, yy = threadIdx.x >> 5;
    #pragma unroll
    for (int i = 0; i < 32; i += 8)
        tile[yy + i][x] = S[(size_t)(k0 + yy + i) * 512 + c0 + x];
    __syncthreads();
    #pragma unroll
    for (int i = 0; i < 32; i += 8) {
        int dd = yy + i;
        WT3[(size_t)(s * 512 + c0 + dd) * H_DIM + k0 + x] = f2bf(tile[x][dd]);
    }
}

__global__ __launch_bounds__(256) void k_trg(const float* __restrict__ in,
                                             float* __restrict__ out) {
    __shared__ float tile[32][33];
    const int r0 = blockIdx.x * 32, c0 = blockIdx.y * 32;
    const int x = threadIdx.x & 31, yy = threadIdx.x >> 5;
    #pragma unroll
    for (int i = 0; i < 32; i += 8) {
        int r = r0 + yy + i;
        if (r < L_CTX) tile[yy + i][x] = in[(size_t)r * CTXD + c0 + x];
    }
    __syncthreads();
    #pragma unroll
    for (int i = 0; i < 32; i += 8) {
        int dd = yy + i;
        if (r0 + x < L_CTX) out[(size_t)(c0 + dd) * L_CTX + r0 + x] = tile[x][dd];
    }
}

// ---------- persistent recurrent kernel (64 blocks x 1024 threads) ----------

struct LP {
    const float *c0, *v, *v2, *bv, *bv2, *bhist, *h0;
    const int* parent;
    float* ws;
    float* out;
};

__global__ __launch_bounds__(NTHR) void lstm_loop(LP p) {
    const int b    = blockIdx.x;
    const int tid  = threadIdx.x;
    const int lane = tid & 63, wv = tid >> 6;   // 16 waves

    float* XWb   = p.ws + OFF_XWB;
    float* ctxW  = p.ws + OFF_CTXW;
    float* ctxT  = p.ws + OFF_CTXT;
    float* u     = p.ws + OFF_U;
    float* w     = p.ws + OFF_W;
    float* eC_g  = p.ws + OFF_EC;
    float* eH_g  = p.ws + OFF_EH;
    float* ctxv  = p.ws + OFF_CTXV;
    float* hctx  = p.ws + OFF_HCTX;
    float* hbuf  = p.ws + OFF_HBUF;
    float* hist  = p.ws + OFF_HIST;
    float* histT = p.ws + OFF_HISTT;
    float* histW = p.ws + OFF_HISTW;
    const unsigned short* W4T = (const unsigned short*)(p.ws + OFF_W4T);
    const unsigned short* WT3 = (const unsigned short*)(p.ws + OFF_WT3);
    unsigned* bar = (unsigned*)(p.ws + OFF_BAR);

    __shared__ float xs[KTOT];       // [h | par_h | hctx | ctxv]
    __shared__ float us_[512], ws_[512], vs_[512], v2s_[512];
    __shared__ float aC[256], aH[256];
    __shared__ float red[64];
    __shared__ float zs[64];
    __shared__ float sc[4];

    // stage constants v, v2; stage h0
    if (tid < 512) vs_[tid] = p.v[tid]; else v2s_[tid - 512] = p.v2[tid - 512];
    xs[tid] = p.h0[tid];
    __syncthreads();

    // ---- prologue: u = Wh^T h0 ; w = Whh^T h0 + bhist ----
    {
        int j = b * 16 + wv;                       // [0,1024)
        const us8* wr = (const us8*)(WT3 + (size_t)j * H_DIM) + lane * 2;
        us8 a0 = wr[0], a1 = wr[1];
        float s = 0.f;
        #pragma unroll
        for (int k = 0; k < 8; ++k) s += bf2f(a0[k]) * xs[lane * 16 + k];
        #pragma unroll
        for (int k = 0; k < 8; ++k) s += bf2f(a1[k]) * xs[lane * 16 + 8 + k];
        s = wred(s);
        if (lane == 0) {
            if (j < A_DIM) st_ag(u + j, s);
            else           st_ag(w + j - A_DIM, s + p.bhist[j - A_DIM]);
        }
        if (b == 0) st_ag(hbuf + tid, p.h0[tid]);
    }
    unsigned ph = 1;
    gbar(bar, b, ph++);

    // GEMV thread mapping: wave wv owns 4 cols; 16 lanes (sub) per col.
    const int colg = b * 64 + (wv << 2) + (lane >> 4);  // global z-column
    const int sub  = lane & 15;
    const us8* Wcol = (const us8*)(W4T + (size_t)colg * KTOT);

    for (int t = 0; t < T_STEPS; ++t) {
        float g0 = 0.f, g1 = 0.f, g2 = 0.f, g3 = 0.f;  // GEMV partial accumulators

        // ---------------- P1: stage, partial GEMV (Uh,Ph), logits ----------------
        {
            // stage par row (xs[0..1024) already holds h from P4/prologue)
            const int pt = p.parent[t];
            xs[1024 + tid] = (t > 0) ? ld_ag(hist + (size_t)pt * H_DIM + tid) : 0.f;
            if (tid < 512) us_[tid] = ld_ag(u + tid);
            else           ws_[tid - 512] = ld_ag(w + tid - 512);
            __syncthreads();

            // partial GEMV over k in [0,2048): 16 chunks, lane-interleaved
            #pragma unroll
            for (int i = 0; i < 16; ++i) {
                const int k0 = i * 128 + sub * 8;
                us8 w8 = Wcol[(i << 4) + sub];
                const float* xk = xs + k0;
                float d0 = bf2f(w8[0])*xk[0] + bf2f(w8[1])*xk[1]
                         + bf2f(w8[2])*xk[2] + bf2f(w8[3])*xk[3];
                float d1 = bf2f(w8[4])*xk[4] + bf2f(w8[5])*xk[5]
                         + bf2f(w8[6])*xk[6] + bf2f(w8[7])*xk[7];
                if ((i & 3) == 0)      { g0 += d0; g0 += d1; }
                else if ((i & 3) == 1) { g1 += d0; g1 += d1; }
                else if ((i & 3) == 2) { g2 += d0; g2 += d1; }
                else                   { g3 += d0; g3 += d1; }
            }

            // logits (one per (block,wave) slot)
            const int idx = b * 16 + wv;
            if (idx < L_CTX) {
                const float4* cw = (const float4*)(ctxW + (size_t)idx * A_DIM) + lane * 2;
                float4 c0v = cw[0], c1v = cw[1];
                const int i0 = lane * 8;
                float e = tanhf(c0v.x + us_[i0+0]) * vs_[i0+0]
                        + tanhf(c0v.y + us_[i0+1]) * vs_[i0+1]
                        + tanhf(c0v.z + us_[i0+2]) * vs_[i0+2]
                        + tanhf(c0v.w + us_[i0+3]) * vs_[i0+3]
                        + tanhf(c1v.x + us_[i0+4]) * vs_[i0+4]
                        + tanhf(c1v.y + us_[i0+5]) * vs_[i0+5]
                        + tanhf(c1v.z + us_[i0+6]) * vs_[i0+6]
                        + tanhf(c1v.w + us_[i0+7]) * vs_[i0+7];
                e = wred(e);
                if (lane == 0) st_ag(eC_g + idx, e + p.bv[0]);
            }
            const int j = idx - 512;
            if (j >= 0 && j < t) {
                const int i0 = lane * 8;
                float e = 0.f;
                #pragma unroll
                for (int k = 0; k < 8; ++k) {
                    float hw = ld_ag(histW + (size_t)j * A_DIM + i0 + k);
                    e += tanhf(hw + ws_[i0 + k]) * v2s_[i0 + k];
                }
                e = wred(e);
                if (lane == 0) st_ag(eH_g + j, e + p.bv2[0]);
            }
        }
        gbar(bar, b, ph++);  // S1

        // ---------------- P2: softmaxes + weighted sums ----------------
        if (tid < L_CTX) aC[tid] = ld_ag(eC_g + tid);
        if (tid < t)     aH[tid] = ld_ag(eH_g + tid);
        __syncthreads();
        {
            float pC = (tid < L_CTX) ? aC[tid] : -3e38f;
            float pH = (tid < t)     ? aH[tid] : -3e38f;
            #pragma unroll
            for (int off = 32; off; off >>= 1) {
                pC = fmaxf(pC, __shfl_down(pC, off));
                pH = fmaxf(pH, __shfl_down(pH, off));
            }
            if (lane == 0) { red[wv] = pC; red[16 + wv] = pH; }
            __syncthreads();
            if (tid == 0) { float m = -3e38f; for (int g = 0; g < 16; ++g) m = fmaxf(m, red[g]); sc[0] = m; }
            if (tid == 1) { float m = -3e38f; for (int g = 0; g < 16; ++g) m = fmaxf(m, red[16 + g]); sc[1] = m; }
            __syncthreads();
            const float mC = sc[0], mH = sc[1];
            float sCp = 0.f, sHp = 0.f;
            if (tid < L_CTX) { float x = __expf(aC[tid] - mC); aC[tid] = x; sCp = x; }
            if (tid < t)     { float x = __expf(aH[tid] - mH); aH[tid] = x; sHp = x; }
            sCp = wred(sCp); sHp = wred(sHp);
            if (lane == 0) { red[wv] = sCp; red[16 + wv] = sHp; }
            __syncthreads();
            if (tid == 0) { float s = 0.f; for (int g = 0; g < 16; ++g) s += red[g]; sc[2] = s; }
            if (tid == 1) { float s = 0.f; for (int g = 0; g < 16; ++g) s += red[16 + g]; sc[3] = s; }
            __syncthreads();
            const float rC = 1.f / sc[2];
            const float rH = (t > 0) ? 1.f / sc[3] : 0.f;

            if (wv < 8) {                          // ctx_vec: dim d = b*8+wv
                const int d = b * 8 + wv;
                float s = 0.f;
                for (int l = lane; l < L_CTX; l += 64)
                    s += aC[l] * ctxT[(size_t)d * L_CTX + l];
                s = wred(s);
                if (lane == 0) {
                    float val = s * rC;
                    st_ag(ctxv + d, val);
                    p.out[(size_t)T_STEPS * H_DIM + (size_t)t * CTXD + d] = val;
                }
            }
            {                                      // h_ctx: dim d2 = b*16+wv
                const int d2 = b * 16 + wv;
                if (t == 0) {
                    if (lane == 0) st_ag(hctx + d2, 0.f);
                } else {
                    float s = 0.f;
                    for (int j = lane; j < t; j += 64)
                        s += aH[j] * ld_ag(histT + (size_t)d2 * T_STEPS + j);
                    s = wred(s);
                    if (lane == 0) st_ag(hctx + d2, s * rH);
                }
            }
        }
        gbar(bar, b, ph++);  // S2

        // ---------------- P3: finish GEMV (Hh,Cc) + gates ----------------
        {
            xs[2048 + tid] = ld_ag(hctx + tid);                     // hctx
            if (tid < 512) xs[3072 + tid] = ld_ag(ctxv + tid);      // ctxv
            __syncthreads();

            #pragma unroll
            for (int i = 0; i < 12; ++i) {
                const int k0 = 2048 + i * 128 + sub * 8;
                us8 w8 = Wcol[(k0 >> 3)];
                const float* xk = xs + k0;
                float d0 = bf2f(w8[0])*xk[0] + bf2f(w8[1])*xk[1]
                         + bf2f(w8[2])*xk[2] + bf2f(w8[3])*xk[3];
                float d1 = bf2f(w8[4])*xk[4] + bf2f(w8[5])*xk[5]
                         + bf2f(w8[6])*xk[6] + bf2f(w8[7])*xk[7];
                if ((i & 3) == 0)      { g0 += d0; g0 += d1; }
                else if ((i & 3) == 1) { g1 += d0; g1 += d1; }
                else if ((i & 3) == 2) { g2 += d0; g2 += d1; }
                else                   { g3 += d0; g3 += d1; }
            }
            float z = (g0 + g1) + (g2 + g3);
            z += __shfl_down(z, 8, 16);
            z += __shfl_down(z, 4, 16);
            z += __shfl_down(z, 2, 16);
            z += __shfl_down(z, 1, 16);
            if (sub == 0) zs[(wv << 2) + (lane >> 4)] = z;
            __syncthreads();
            if (tid < 16) {
                const int d = b * 16 + tid;
                float zi = zs[4 * tid + 0] + XWb[(size_t)t * G4 + 0 * 1024 + d];
                float zf = zs[4 * tid + 1] + XWb[(size_t)t * G4 + 1 * 1024 + d];
                float zc = zs[4 * tid + 2] + XWb[(size_t)t * G4 + 2 * 1024 + d];
                float zo = zs[4 * tid + 3] + XWb[(size_t)t * G4 + 3 * 1024 + d];
                float cn = sigmoidf_(zf) * p.c0[d] + sigmoidf_(zi) * tanhf(zc);
                float hn = sigmoidf_(zo) * tanhf(cn);
                st_ag(hbuf + d, hn);
                st_ag(hist + (size_t)t * H_DIM + d, hn);
                st_ag(histT + (size_t)d * T_STEPS + t, hn);
                p.out[(size_t)t * H_DIM + d] = hn;
            }
        }
        gbar(bar, b, ph++);  // S3

        // ---------------- P4: u/w/histW from new h (also re-stages xs[0..1024)) ----
        xs[tid] = ld_ag(hbuf + tid);
        __syncthreads();
        {
            #pragma unroll
            for (int rr = 0; rr < 2; ++rr) {
                const int r = (rr == 0) ? wv : 16 + wv;
                if (rr == 1 && wv >= 8) break;
                const int j = b * 24 + r;          // [0,1536)
                const us8* wr = (const us8*)(WT3 + (size_t)j * H_DIM) + lane * 2;
                us8 a0 = wr[0], a1 = wr[1];
                float s = 0.f;
                #pragma unroll
                for (int k = 0; k < 8; ++k) s += bf2f(a0[k]) * xs[lane * 16 + k];
                #pragma unroll
                for (int k = 0; k < 8; ++k) s += bf2f(a1[k]) * xs[lane * 16 + 8 + k];
                s = wred(s);
                if (lane == 0) {
                    if (j < A_DIM)          st_ag(u + j, s);
                    else if (j < 2 * A_DIM) st_ag(w + j - A_DIM, s + p.bhist[j - A_DIM]);
                    else                    st_ag(histW + (size_t)t * A_DIM + (j - 2 * A_DIM), s);
                }
            }
        }
        gbar(bar, b, ph++);  // S4
    }
}

// ---------- host ----------

extern "C" void kernel_launch(void* const* d_in, const int* in_sizes, int n_in,
                              void* d_out, int out_size, void* d_ws, size_t ws_size,
                              hipStream_t stream) {
    if (ws_size < (size_t)WS_FLOATS * sizeof(float)) return;  // OOB insurance

    const float* X      = (const float*)d_in[0];
    const float* ctx    = (const float*)d_in[1];
    const float* h0     = (const float*)d_in[2];
    const float* c0     = (const float*)d_in[3];
    const int*   parent = (const int*)  d_in[4];
    const float* Wx     = (const float*)d_in[5];
    const float* Uh     = (const float*)d_in[6];
    const float* Cc     = (const float*)d_in[7];
    const float* Ph     = (const float*)d_in[8];
    const float* Hh     = (const float*)d_in[9];
    const float* b4     = (const float*)d_in[10];
    const float* Wctx   = (const float*)d_in[11];
    const float* bctx   = (const float*)d_in[12];
    const float* Wh     = (const float*)d_in[13];
    const float* v      = (const float*)d_in[14];
    const float* bv     = (const float*)d_in[15];
    const float* Whist  = (const float*)d_in[16];
    const float* bhist  = (const float*)d_in[17];
    const float* Whh    = (const float*)d_in[18];
    const float* v2     = (const float*)d_in[19];
    const float* bv2    = (const float*)d_in[20];
    float* ws  = (float*)d_ws;
    float* out = (float*)d_out;

    // zero barrier flags every call (deterministic across graph replays)
    hipMemsetAsync((char*)d_ws + (size_t)OFF_BAR * sizeof(float), 0, 1024, stream);

    hipLaunchKernelGGL(k_xwb,    dim3(16, 32),     dim3(256), 0, stream, X,   Wx,   b4,   ws + OFF_XWB);
    hipLaunchKernelGGL(k_ctxw,   dim3(2, 25),      dim3(256), 0, stream, ctx, Wctx, bctx, ws + OFF_CTXW);
    hipLaunchKernelGGL(k_trg,    dim3(7, 16),      dim3(256), 0, stream, ctx, ws + OFF_CTXT);
    hipLaunchKernelGGL(k_packW4, dim3(112, 32, 4), dim3(256), 0, stream, Uh, Ph, Hh, Cc,
                       (unsigned short*)(ws + OFF_W4T));
    hipLaunchKernelGGL(k_packW3, dim3(32, 16, 3),  dim3(256), 0, stream, Wh, Whh, Whist,
                       (unsigned short*)(ws + OFF_WT3));

    LP p{c0, v, v2, bv, bv2, bhist, h0, parent, ws, out};
    hipLaunchKernelGGL(lstm_loop, dim3(NBLK), dim3(NTHR), 0, stream, p);
}

// Round 9
// 10856.834 us; speedup vs baseline: 1.6145x; 1.6145x over previous
//
#include <hip/hip_runtime.h>

#define T_STEPS 256
#define H_DIM   1024
#define L_CTX   200
#define CTXD    512
#define A_DIM   512
#define G4      4096
#define KTOT    3584   // 1024 h + 1024 par + 1024 hctx + 512 ctx
#define NBLK    64
#define NTHR    512

typedef __attribute__((ext_vector_type(8))) unsigned short us8;

// ws offsets (floats)
#define OFF_XWB    0                           // 256*4096
#define OFF_CTXW   (OFF_XWB   + T_STEPS*G4)    // 200*512
#define OFF_CTXT   (OFF_CTXW  + L_CTX*A_DIM)   // 512*200
#define OFF_U      (OFF_CTXT  + CTXD*L_CTX)    // 512
#define OFF_W      (OFF_U     + A_DIM)         // 512
#define OFF_EC     (OFF_W     + A_DIM)         // 256
#define OFF_EH     (OFF_EC    + 256)           // 256
#define OFF_CTXV   (OFF_EH    + 256)           // 512
#define OFF_HCTX   (OFF_CTXV  + CTXD)          // 1024
#define OFF_HBUF   (OFF_HCTX  + H_DIM)         // 1024
#define OFF_HIST   (OFF_HBUF  + H_DIM)         // 256*1024
#define OFF_HISTT  (OFF_HIST  + T_STEPS*H_DIM) // 1024*256
#define OFF_HISTW  (OFF_HISTT + H_DIM*T_STEPS) // 256*512
#define OFF_W4T    (OFF_HISTW + T_STEPS*A_DIM) // 4096*3584 bf16
#define OFF_WT3    (OFF_W4T   + G4*KTOT/2)     // 1536*1024 bf16
#define OFF_BAR    (OFF_WT3   + 1536*H_DIM/2)  // 64 flag dwords
#define WS_FLOATS  (OFF_BAR   + 256)

__device__ __forceinline__ float sigmoidf_(float x) { return 1.f / (1.f + __expf(-x)); }
__device__ __forceinline__ float bf2f(unsigned short h) { return __uint_as_float((unsigned)h << 16); }
__device__ __forceinline__ unsigned short f2bf(float x) {
    unsigned u = __float_as_uint(x);
    return (unsigned short)((u + 0x7FFFu + ((u >> 16) & 1u)) >> 16);
}
// coherent-point (agent-scope) accesses: bypass non-coherent per-XCD L2
__device__ __forceinline__ float ld_ag(const float* p) {
    return __hip_atomic_load((float*)p, __ATOMIC_RELAXED, __HIP_MEMORY_SCOPE_AGENT);
}
__device__ __forceinline__ void st_ag(float* p, float v) {
    __hip_atomic_store(p, v, __ATOMIC_RELAXED, __HIP_MEMORY_SCOPE_AGENT);
}
__device__ __forceinline__ float wred(float x) {
    #pragma unroll
    for (int off = 32; off; off >>= 1) x += __shfl_down(x, off);
    return x;
}
__device__ __forceinline__ float wredmax(float x) {
    #pragma unroll
    for (int off = 32; off; off >>= 1) x = fmaxf(x, __shfl_down(x, off));
    return x;
}

// RMW-free flag barrier: block b STOREs its phase to bar[b]; wave 0 gather-
// polls all 64 flags (one 64-lane relaxed load per round, s_sleep-throttled).
// __syncthreads() before arrival drains vmcnt => prior st_ag data reached the
// coherent point before the flag store issues.
__device__ __forceinline__ void gbar(unsigned* bar, int b, unsigned ph) {
    __syncthreads();
    if (threadIdx.x < 64) {
        if (threadIdx.x == 0)
            __hip_atomic_store(bar + b, ph, __ATOMIC_RELAXED, __HIP_MEMORY_SCOPE_AGENT);
        int spins = 0;
        unsigned vflag;
        do {
            vflag = __hip_atomic_load(bar + threadIdx.x, __ATOMIC_RELAXED, __HIP_MEMORY_SCOPE_AGENT);
            if (++spins > 30000) break;  // hang insurance
            __builtin_amdgcn_s_sleep(1);
        } while (__any(vflag < ph));
    }
    __syncthreads();
}

// ---------- prep kernels ----------

__global__ __launch_bounds__(256) void k_xwb(const float* __restrict__ X,
                                             const float* __restrict__ Wx,
                                             const float* __restrict__ b4,
                                             float* __restrict__ XWb) {
    int c  = blockIdx.x * 256 + threadIdx.x;
    int r0 = blockIdx.y * 8;
    float acc[8] = {0,0,0,0,0,0,0,0};
    for (int k = 0; k < 512; ++k) {
        float wv = Wx[(size_t)k * G4 + c];
        #pragma unroll
        for (int r = 0; r < 8; ++r) acc[r] += X[(r0 + r) * 512 + k] * wv;
    }
    float bb = b4[c];
    #pragma unroll
    for (int r = 0; r < 8; ++r) XWb[(size_t)(r0 + r) * G4 + c] = acc[r] + bb;
}

__global__ __launch_bounds__(256) void k_ctxw(const float* __restrict__ ctx,
                                              const float* __restrict__ Wctx,
                                              const float* __restrict__ bctx,
                                              float* __restrict__ ctxW) {
    int a  = blockIdx.x * 256 + threadIdx.x;
    int l0 = blockIdx.y * 8;
    float acc[8] = {0,0,0,0,0,0,0,0};
    for (int k = 0; k < 512; ++k) {
        float wv = Wctx[(size_t)k * A_DIM + a];
        #pragma unroll
        for (int r = 0; r < 8; ++r) acc[r] += ctx[(l0 + r) * CTXD + k] * wv;
    }
    float bb = bctx[a];
    #pragma unroll
    for (int r = 0; r < 8; ++r) ctxW[(l0 + r) * A_DIM + a] = acc[r] + bb;
}

__global__ __launch_bounds__(256) void k_packW4(const float* __restrict__ Uh,
                                                const float* __restrict__ Ph,
                                                const float* __restrict__ Hh,
                                                const float* __restrict__ Cc,
                                                unsigned short* __restrict__ W4T) {
    __shared__ float tile[32][33];
    const int k0 = blockIdx.x * 32, d0 = blockIdx.y * 32, q = blockIdx.z;
    const int x = threadIdx.x & 31, yy = threadIdx.x >> 5;
    const int c = q * 1024 + d0 + x;
    #pragma unroll
    for (int i = 0; i < 32; i += 8) {
        int ka = k0 + yy + i;
        const float* src; int kk;
        if (ka < 1024)      { src = Uh; kk = ka; }
        else if (ka < 2048) { src = Ph; kk = ka - 1024; }
        else if (ka < 3072) { src = Hh; kk = ka - 2048; }
        else                { src = Cc; kk = ka - 3072; }
        tile[yy + i][x] = src[(size_t)kk * G4 + c];
    }
    __syncthreads();
    #pragma unroll
    for (int i = 0; i < 32; i += 8) {
        int dd = yy + i;
        int col = 4 * (d0 + dd) + q;
        W4T[(size_t)col * KTOT + k0 + x] = f2bf(tile[x][dd]);
    }
}

__global__ __launch_bounds__(256) void k_packW3(const float* __restrict__ Wh,
                                                const float* __restrict__ Whh,
                                                const float* __restrict__ Whist,
                                                unsigned short* __restrict__ WT3) {
    __shared__ float tile[32][33];
    const int k0 = blockIdx.x * 32, c0 = blockIdx.y * 32, s = blockIdx.z;
    const float* S = (s == 0) ? Wh : (s == 1) ? Whh : Whist;
    const int x = threadIdx.x & 31, yy = threadIdx.x >> 5;
    #pragma unroll
    for (int i = 0; i < 32; i += 8)
        tile[yy + i][x] = S[(size_t)(k0 + yy + i) * 512 + c0 + x];
    __syncthreads();
    #pragma unroll
    for (int i = 0; i < 32; i += 8) {
        int dd = yy + i;
        WT3[(size_t)(s * 512 + c0 + dd) * H_DIM + k0 + x] = f2bf(tile[x][dd]);
    }
}

__global__ __launch_bounds__(256) void k_trg(const float* __restrict__ in,
                                             float* __restrict__ out) {
    __shared__ float tile[32][33];
    const int r0 = blockIdx.x * 32, c0 = blockIdx.y * 32;
    const int x = threadIdx.x & 31, yy = threadIdx.x >> 5;
    #pragma unroll
    for (int i = 0; i < 32; i += 8) {
        int r = r0 + yy + i;
        if (r < L_CTX) tile[yy + i][x] = in[(size_t)r * CTXD + c0 + x];
    }
    __syncthreads();
    #pragma unroll
    for (int i = 0; i < 32; i += 8) {
        int dd = yy + i;
        if (r0 + x < L_CTX) out[(size_t)(c0 + dd) * L_CTX + r0 + x] = tile[x][dd];
    }
}

// ---------- persistent recurrent kernel (64 blocks x 512 threads) ----------

struct LP {
    const float *c0, *v, *v2, *bv, *bv2, *bhist, *h0;
    const int* parent;
    float* ws;
    float* out;
};

__global__ __launch_bounds__(NTHR, 2) void lstm_loop(LP p) {
    const int b    = blockIdx.x;
    const int tid  = threadIdx.x;
    const int lane = tid & 63, wv = tid >> 6;   // 8 waves

    float* XWb   = p.ws + OFF_XWB;
    float* ctxW  = p.ws + OFF_CTXW;
    float* ctxT  = p.ws + OFF_CTXT;
    float* u     = p.ws + OFF_U;
    float* w     = p.ws + OFF_W;
    float* eC_g  = p.ws + OFF_EC;
    float* eH_g  = p.ws + OFF_EH;
    float* ctxv  = p.ws + OFF_CTXV;
    float* hctx  = p.ws + OFF_HCTX;
    float* hbuf  = p.ws + OFF_HBUF;
    float* hist  = p.ws + OFF_HIST;
    float* histT = p.ws + OFF_HISTT;
    float* histW = p.ws + OFF_HISTW;
    const unsigned short* W4T = (const unsigned short*)(p.ws + OFF_W4T);
    const unsigned short* WT3 = (const unsigned short*)(p.ws + OFF_WT3);
    unsigned* bar = (unsigned*)(p.ws + OFF_BAR);

    __shared__ float xs[KTOT];       // [h | par_h | hctx | ctxv]
    __shared__ float us_[512], ws_[512], vs_[512], v2s_[512];
    __shared__ float aC[256], aH[256];
    __shared__ float red[16];
    __shared__ float zs1[64], zs[64];
    __shared__ float sc[4];

    // stage constants; stage h0 into xs[0..1024)
    vs_[tid] = p.v[tid];  v2s_[tid] = p.v2[tid];
    xs[tid] = p.h0[tid];  xs[512 + tid] = p.h0[512 + tid];
    __syncthreads();

    // ---- prologue: u = Wh^T h0 ; w = Whh^T h0 + bhist (2 rows/wave) ----
    #pragma unroll
    for (int rr = 0; rr < 2; ++rr) {
        int j = b * 16 + wv * 2 + rr;              // [0,1024)
        const us8* wr = (const us8*)(WT3 + (size_t)j * H_DIM) + lane * 2;
        us8 a0 = wr[0], a1 = wr[1];
        float s = 0.f;
        #pragma unroll
        for (int k = 0; k < 8; ++k) s += bf2f(a0[k]) * xs[lane * 16 + k];
        #pragma unroll
        for (int k = 0; k < 8; ++k) s += bf2f(a1[k]) * xs[lane * 16 + 8 + k];
        s = wred(s);
        if (lane == 0) {
            if (j < A_DIM) st_ag(u + j, s);
            else           st_ag(w + j - A_DIM, s + p.bhist[j - A_DIM]);
        }
    }
    unsigned ph = 1;
    gbar(bar, b, ph++);

    // GEMV mapping: 64 cols/block; within a wave, 8 cols x 8 subs.
    const int cg   = (wv << 3) + (lane >> 3);   // local col [0,64)
    const int sub  = lane & 7;
    const us8* Wcol = (const us8*)(W4T + (size_t)(b * 64 + cg) * KTOT);

    for (int t = 0; t < T_STEPS; ++t) {
        // ---------------- P1: stage par/u/w, partial GEMV (Uh,Ph), logits ----------------
        {
            const int pt = p.parent[t];
            if (t > 0) {
                xs[1024 + tid] = ld_ag(hist + (size_t)pt * H_DIM + tid);
                xs[1536 + tid] = ld_ag(hist + (size_t)pt * H_DIM + 512 + tid);
            } else {
                xs[1024 + tid] = 0.f; xs[1536 + tid] = 0.f;
            }
            us_[tid] = ld_ag(u + tid);
            ws_[tid] = ld_ag(w + tid);
            __syncthreads();

            // GEMV over k in [0,2048): 32 us8-chunks per sub, lane-interleaved
            float a0 = 0.f, a1 = 0.f;
            #pragma unroll 4
            for (int i = 0; i < 32; ++i) {
                const int c = i * 8 + sub;
                us8 w8 = Wcol[c];
                const float* xk = xs + c * 8;
                float d0 = bf2f(w8[0])*xk[0] + bf2f(w8[1])*xk[1]
                         + bf2f(w8[2])*xk[2] + bf2f(w8[3])*xk[3];
                float d1 = bf2f(w8[4])*xk[4] + bf2f(w8[5])*xk[5]
                         + bf2f(w8[6])*xk[6] + bf2f(w8[7])*xk[7];
                if (i & 1) a1 += d0 + d1; else a0 += d0 + d1;
            }
            float z1 = a0 + a1;
            z1 += __shfl_down(z1, 4, 8);
            z1 += __shfl_down(z1, 2, 8);
            z1 += __shfl_down(z1, 1, 8);
            if (sub == 0) zs1[cg] = z1;

            // logits: one per (block,wave)
            const int idx = b * 8 + wv;            // [0,512)
            if (idx < L_CTX) {
                const float4* cw = (const float4*)(ctxW + (size_t)idx * A_DIM) + lane * 2;
                float4 c0v = cw[0], c1v = cw[1];
                const int i0 = lane * 8;
                float e = tanhf(c0v.x + us_[i0+0]) * vs_[i0+0]
                        + tanhf(c0v.y + us_[i0+1]) * vs_[i0+1]
                        + tanhf(c0v.z + us_[i0+2]) * vs_[i0+2]
                        + tanhf(c0v.w + us_[i0+3]) * vs_[i0+3]
                        + tanhf(c1v.x + us_[i0+4]) * vs_[i0+4]
                        + tanhf(c1v.y + us_[i0+5]) * vs_[i0+5]
                        + tanhf(c1v.z + us_[i0+6]) * vs_[i0+6]
                        + tanhf(c1v.w + us_[i0+7]) * vs_[i0+7];
                e = wred(e);
                if (lane == 0) st_ag(eC_g + idx, e + p.bv[0]);
            }
            const int j = idx - 256;
            if (j >= 0 && j < t) {
                const int i0 = lane * 8;
                float e = 0.f;
                #pragma unroll
                for (int k = 0; k < 8; ++k) {
                    float hw = ld_ag(histW + (size_t)j * A_DIM + i0 + k);
                    e += tanhf(hw + ws_[i0 + k]) * v2s_[i0 + k];
                }
                e = wred(e);
                if (lane == 0) st_ag(eH_g + j, e + p.bv2[0]);
            }
        }
        gbar(bar, b, ph++);  // S1

        // ---------------- P2: softmaxes + weighted sums ----------------
        if (tid < L_CTX) aC[tid] = ld_ag(eC_g + tid);
        if (tid < t)     aH[tid] = ld_ag(eH_g + tid);
        __syncthreads();
        {
            float pC = (tid < L_CTX) ? aC[tid] : -3e38f;
            float pH = (tid < t)     ? aH[tid] : -3e38f;
            pC = wredmax(pC); pH = wredmax(pH);
            if (lane == 0) { red[wv] = pC; red[8 + wv] = pH; }
            __syncthreads();
            if (tid == 0) { float m = -3e38f; for (int g = 0; g < 8; ++g) m = fmaxf(m, red[g]); sc[0] = m; }
            if (tid == 1) { float m = -3e38f; for (int g = 0; g < 8; ++g) m = fmaxf(m, red[8 + g]); sc[1] = m; }
            __syncthreads();
            const float mC = sc[0], mH = sc[1];
            float sCp = 0.f, sHp = 0.f;
            if (tid < L_CTX) { float x = __expf(aC[tid] - mC); aC[tid] = x; sCp = x; }
            if (tid < t)     { float x = __expf(aH[tid] - mH); aH[tid] = x; sHp = x; }
            sCp = wred(sCp); sHp = wred(sHp);
            if (lane == 0) { red[wv] = sCp; red[8 + wv] = sHp; }
            __syncthreads();
            if (tid == 0) { float s = 0.f; for (int g = 0; g < 8; ++g) s += red[g]; sc[2] = s; }
            if (tid == 1) { float s = 0.f; for (int g = 0; g < 8; ++g) s += red[8 + g]; sc[3] = s; }
            __syncthreads();
            const float rC = 1.f / sc[2];
            const float rH = (t > 0) ? 1.f / sc[3] : 0.f;

            {                                      // ctx_vec: dim d = b*8+wv
                const int d = b * 8 + wv;
                float s = 0.f;
                for (int l = lane; l < L_CTX; l += 64)
                    s += aC[l] * ctxT[(size_t)d * L_CTX + l];
                s = wred(s);
                if (lane == 0) {
                    float val = s * rC;
                    st_ag(ctxv + d, val);
                    p.out[(size_t)T_STEPS * H_DIM + (size_t)t * CTXD + d] = val;
                }
            }
            {                                      // h_ctx: 2 dims/wave (half-wave each)
                const int d2 = b * 16 + wv * 2 + (lane >> 5);
                const int sl = lane & 31;
                if (t == 0) {
                    if (sl == 0) st_ag(hctx + d2, 0.f);
                } else {
                    float s = 0.f;
                    for (int j = sl; j < t; j += 32)
                        s += aH[j] * ld_ag(histT + (size_t)d2 * T_STEPS + j);
                    #pragma unroll
                    for (int off = 16; off; off >>= 1) s += __shfl_down(s, off, 32);
                    if (sl == 0) st_ag(hctx + d2, s * rH);
                }
            }
        }
        gbar(bar, b, ph++);  // S2

        // ---------------- P3: finish GEMV (Hh,Cc) + gates ----------------
        {
            xs[2048 + tid] = ld_ag(hctx + tid);
            xs[2560 + tid] = ld_ag(hctx + 512 + tid);
            xs[3072 + tid] = ld_ag(ctxv + tid);
            __syncthreads();

            float a0 = 0.f, a1 = 0.f;
            #pragma unroll 4
            for (int i = 0; i < 24; ++i) {
                const int c = 256 + i * 8 + sub;
                us8 w8 = Wcol[c];
                const float* xk = xs + c * 8;
                float d0 = bf2f(w8[0])*xk[0] + bf2f(w8[1])*xk[1]
                         + bf2f(w8[2])*xk[2] + bf2f(w8[3])*xk[3];
                float d1 = bf2f(w8[4])*xk[4] + bf2f(w8[5])*xk[5]
                         + bf2f(w8[6])*xk[6] + bf2f(w8[7])*xk[7];
                if (i & 1) a1 += d0 + d1; else a0 += d0 + d1;
            }
            float z2 = a0 + a1;
            z2 += __shfl_down(z2, 4, 8);
            z2 += __shfl_down(z2, 2, 8);
            z2 += __shfl_down(z2, 1, 8);
            if (sub == 0) zs[cg] = zs1[cg] + z2;
            __syncthreads();
            if (tid < 16) {
                const int d = b * 16 + tid;
                float zi = zs[4 * tid + 0] + XWb[(size_t)t * G4 + 0 * 1024 + d];
                float zf = zs[4 * tid + 1] + XWb[(size_t)t * G4 + 1 * 1024 + d];
                float zc = zs[4 * tid + 2] + XWb[(size_t)t * G4 + 2 * 1024 + d];
                float zo = zs[4 * tid + 3] + XWb[(size_t)t * G4 + 3 * 1024 + d];
                float cn = sigmoidf_(zf) * p.c0[d] + sigmoidf_(zi) * tanhf(zc);
                float hn = sigmoidf_(zo) * tanhf(cn);
                st_ag(hbuf + d, hn);
                st_ag(hist + (size_t)t * H_DIM + d, hn);
                st_ag(histT + (size_t)d * T_STEPS + t, hn);
                p.out[(size_t)t * H_DIM + d] = hn;
            }
        }
        gbar(bar, b, ph++);  // S3

        // ---------------- P4: u/w/histW from new h (re-stages xs[0..1024)) ----------------
        xs[tid] = ld_ag(hbuf + tid);
        xs[512 + tid] = ld_ag(hbuf + 512 + tid);
        __syncthreads();
        {
            #pragma unroll
            for (int rr = 0; rr < 3; ++rr) {
                const int j = b * 24 + wv * 3 + rr;   // [0,1536)
                const us8* wr = (const us8*)(WT3 + (size_t)j * H_DIM) + lane * 2;
                us8 a0 = wr[0], a1 = wr[1];
                float s = 0.f;
                #pragma unroll
                for (int k = 0; k < 8; ++k) s += bf2f(a0[k]) * xs[lane * 16 + k];
                #pragma unroll
                for (int k = 0; k < 8; ++k) s += bf2f(a1[k]) * xs[lane * 16 + 8 + k];
                s = wred(s);
                if (lane == 0) {
                    if (j < A_DIM)          st_ag(u + j, s);
                    else if (j < 2 * A_DIM) st_ag(w + j - A_DIM, s + p.bhist[j - A_DIM]);
                    else                    st_ag(histW + (size_t)t * A_DIM + (j - 2 * A_DIM), s);
                }
            }
        }
        gbar(bar, b, ph++);  // S4
    }
}

// ---------- host ----------

extern "C" void kernel_launch(void* const* d_in, const int* in_sizes, int n_in,
                              void* d_out, int out_size, void* d_ws, size_t ws_size,
                              hipStream_t stream) {
    if (ws_size < (size_t)WS_FLOATS * sizeof(float)) return;  // OOB insurance

    const float* X      = (const float*)d_in[0];
    const float* ctx    = (const float*)d_in[1];
    const float* h0     = (const float*)d_in[2];
    const float* c0     = (const float*)d_in[3];
    const int*   parent = (const int*)  d_in[4];
    const float* Wx     = (const float*)d_in[5];
    const float* Uh     = (const float*)d_in[6];
    const float* Cc     = (const float*)d_in[7];
    const float* Ph     = (const float*)d_in[8];
    const float* Hh     = (const float*)d_in[9];
    const float* b4     = (const float*)d_in[10];
    const float* Wctx   = (const float*)d_in[11];
    const float* bctx   = (const float*)d_in[12];
    const float* Wh     = (const float*)d_in[13];
    const float* v      = (const float*)d_in[14];
    const float* bv     = (const float*)d_in[15];
    const float* Whist  = (const float*)d_in[16];
    const float* bhist  = (const float*)d_in[17];
    const float* Whh    = (const float*)d_in[18];
    const float* v2     = (const float*)d_in[19];
    const float* bv2    = (const float*)d_in[20];
    float* ws  = (float*)d_ws;
    float* out = (float*)d_out;

    // zero barrier flags every call (deterministic across graph replays)
    hipMemsetAsync((char*)d_ws + (size_t)OFF_BAR * sizeof(float), 0, 1024, stream);

    hipLaunchKernelGGL(k_xwb,    dim3(16, 32),     dim3(256), 0, stream, X,   Wx,   b4,   ws + OFF_XWB);
    hipLaunchKernelGGL(k_ctxw,   dim3(2, 25),      dim3(256), 0, stream, ctx, Wctx, bctx, ws + OFF_CTXW);
    hipLaunchKernelGGL(k_trg,    dim3(7, 16),      dim3(256), 0, stream, ctx, ws + OFF_CTXT);
    hipLaunchKernelGGL(k_packW4, dim3(112, 32, 4), dim3(256), 0, stream, Uh, Ph, Hh, Cc,
                       (unsigned short*)(ws + OFF_W4T));
    hipLaunchKernelGGL(k_packW3, dim3(32, 16, 3),  dim3(256), 0, stream, Wh, Whh, Whist,
                       (unsigned short*)(ws + OFF_WT3));

    LP p{c0, v, v2, bv, bv2, bhist, h0, parent, ws, out};
    hipLaunchKernelGGL(lstm_loop, dim3(NBLK), dim3(NTHR), 0, stream, p);
}